// Round 1
// baseline (539.447 us; speedup 1.0000x reference)
//
#include <hip/hip_runtime.h>

#define HD 10
#define C2 20
#define PIX (192*192)
#define NB 8
#define NPIX (NB*PIX)
#define CHW (NB*HD*PIX)
#define EPSB 1e-5f

__device__ __forceinline__ float sigm(float x) {
    return __builtin_amdgcn_rcpf(1.0f + __expf(-x));
}
__device__ __forceinline__ float tanh_fast(float x) {
    // tanh(x) = 1 - 2/(exp(2x)+1); saturates correctly at +/-inf
    return 1.0f - 2.0f * __builtin_amdgcn_rcpf(1.0f + __expf(2.0f * x));
}

__device__ __forceinline__ void gru10(const float h[HD], const float x[HD],
    const float* __restrict__ Wg, const float* __restrict__ Bg,
    const float* __restrict__ Wc, const float* __restrict__ Bc, float o_[HD])
{
    float g[C2];
    #pragma unroll
    for (int o = 0; o < C2; ++o) {
        float a = Bg[o];
        #pragma unroll
        for (int k = 0; k < HD; ++k) a = fmaf(Wg[o*C2 + k], x[k], a);
        #pragma unroll
        for (int k = 0; k < HD; ++k) a = fmaf(Wg[o*C2 + HD + k], h[k], a);
        g[o] = sigm(a);
    }
    float rh[HD];
    #pragma unroll
    for (int k = 0; k < HD; ++k) rh[k] = g[k] * h[k];
    #pragma unroll
    for (int o = 0; o < HD; ++o) {
        float a = Bc[o];
        #pragma unroll
        for (int k = 0; k < HD; ++k) a = fmaf(Wc[o*C2 + k], x[k], a);
        #pragma unroll
        for (int k = 0; k < HD; ++k) a = fmaf(Wc[o*C2 + HD + k], rh[k], a);
        float c = tanh_fast(a);
        float u = g[HD + o];
        o_[o] = fmaf(u, c - h[o], h[o]);   // (1-u)*h + u*c
    }
}

__global__ __launch_bounds__(256) void half_graph_fused(
    const float* __restrict__ xf, const float* __restrict__ xh, const float* __restrict__ xp,
    const float* __restrict__ h_att, const float* __restrict__ p_att,
    const float* __restrict__ dW1, const float* __restrict__ dbn1,
    const float* __restrict__ dW2, const float* __restrict__ dbn2,
    const float* __restrict__ uW1, const float* __restrict__ ubn1,
    const float* __restrict__ uW2, const float* __restrict__ ubn2,
    const float* __restrict__ lW1, const float* __restrict__ lbn1,
    const float* __restrict__ lW2, const float* __restrict__ lbn2,
    const float* __restrict__ guWg, const float* __restrict__ gubg,
    const float* __restrict__ guWc, const float* __restrict__ gubc,
    const float* __restrict__ glWg, const float* __restrict__ glbg,
    const float* __restrict__ glWc, const float* __restrict__ glbc,
    float* __restrict__ out)
{
    __shared__ float sdW1[C2*C2], sdB1[C2], sdW2[HD*C2], sdB2[HD];
    __shared__ float suW1[C2*C2], suB1[C2], suW2[HD*C2], suB2[HD];
    __shared__ float slW1[C2*C2], slB1[C2], slW2[HD*C2], slB2[HD];
    __shared__ float sgWg[2][C2*C2], sgBg[2][C2], sgWc[2][HD*C2], sgBc[2][HD];

    const int tid = threadIdx.x;

    // ---- fold BN into conv weights (wave-uniform broadcast reads later) ----
    for (int i = tid; i < C2*C2; i += 256) {
        int o = i / C2;
        float sd = dbn1[o] * rsqrtf(dbn1[3*C2 + o] + EPSB);
        float su = ubn1[o] * rsqrtf(ubn1[3*C2 + o] + EPSB);
        float sl = lbn1[o] * rsqrtf(lbn1[3*C2 + o] + EPSB);
        sdW1[i] = dW1[i] * sd;
        suW1[i] = uW1[i] * su;
        slW1[i] = lW1[i] * sl;
        sgWg[0][i] = guWg[i];
        sgWg[1][i] = glWg[i];
    }
    for (int i = tid; i < HD*C2; i += 256) {
        int o = i / C2;
        float sd = dbn2[o] * rsqrtf(dbn2[3*HD + o] + EPSB);
        float su = ubn2[o] * rsqrtf(ubn2[3*HD + o] + EPSB);
        float sl = lbn2[o] * rsqrtf(lbn2[3*HD + o] + EPSB);
        sdW2[i] = dW2[i] * sd;
        suW2[i] = uW2[i] * su;
        slW2[i] = lW2[i] * sl;
        sgWc[0][i] = guWc[i];
        sgWc[1][i] = glWc[i];
    }
    if (tid < C2) {
        int o = tid;
        float sd = dbn1[o] * rsqrtf(dbn1[3*C2 + o] + EPSB);
        float su = ubn1[o] * rsqrtf(ubn1[3*C2 + o] + EPSB);
        float sl = lbn1[o] * rsqrtf(lbn1[3*C2 + o] + EPSB);
        sdB1[o] = dbn1[C2 + o] - sd * dbn1[2*C2 + o];
        suB1[o] = ubn1[C2 + o] - su * ubn1[2*C2 + o];
        slB1[o] = lbn1[C2 + o] - sl * lbn1[2*C2 + o];
        sgBg[0][o] = gubg[o];
        sgBg[1][o] = glbg[o];
    }
    if (tid < HD) {
        int o = tid;
        float sd = dbn2[o] * rsqrtf(dbn2[3*HD + o] + EPSB);
        float su = ubn2[o] * rsqrtf(ubn2[3*HD + o] + EPSB);
        float sl = lbn2[o] * rsqrtf(lbn2[3*HD + o] + EPSB);
        sdB2[o] = dbn2[HD + o] - sd * dbn2[2*HD + o];
        suB2[o] = ubn2[HD + o] - su * ubn2[2*HD + o];
        slB2[o] = lbn2[HD + o] - sl * lbn2[2*HD + o];
        sgBc[0][o] = gubc[o];
        sgBc[1][o] = glbc[o];
    }
    __syncthreads();

    const int t = blockIdx.x * 256 + tid;      // one pixel per thread
    const int b = t / PIX;                      // uniform per block (PIX % 256 == 0)
    const int s = t - b * PIX;
    const int base  = b * (HD*PIX) + s;         // [B,HD,P] tensors: + c*PIX
    const int abase = b * PIX + s;              // [*,B,1,P] attention maps

    // ---- per-pixel inputs ----
    float vxf[HD], vxh0[HD], vxh1[HD];
    #pragma unroll
    for (int c = 0; c < HD; ++c) {
        vxf[c]  = xf[base + c*PIX];
        vxh0[c] = xh[base + c*PIX];
        vxh1[c] = xh[CHW + base + c*PIX];
    }
    const float ha1 = h_att[NPIX + abase];
    const float ha2 = h_att[2*NPIX + abase];
    const float cau = p_att[NPIX + abase] + p_att[2*NPIX + abase]
                    + p_att[3*NPIX + abase] + p_att[4*NPIX + abase];
    const float cal = p_att[5*NPIX + abase] + p_att[6*NPIX + abase];

    // ---- decomposition blocks (shared dW weights: compute both halves together) ----
    float du[HD], dl[HD];
    {
        float in0[C2], in1[C2];
        #pragma unroll
        for (int c = 0; c < HD; ++c) {
            in0[c] = vxf[c] * ha1;  in0[HD + c] = vxh0[c];
            in1[c] = vxf[c] * ha2;  in1[HD + c] = vxh1[c];
        }
        float h0[C2], h1[C2];
        #pragma unroll
        for (int o = 0; o < C2; ++o) {
            float a0 = sdB1[o], a1 = a0;
            #pragma unroll
            for (int k = 0; k < C2; ++k) {
                float w = sdW1[o*C2 + k];
                a0 = fmaf(w, in0[k], a0);
                a1 = fmaf(w, in1[k], a1);
            }
            h0[o] = fmaxf(a0, 0.f);
            h1[o] = fmaxf(a1, 0.f);
        }
        #pragma unroll
        for (int o = 0; o < HD; ++o) {
            float a0 = sdB2[o], a1 = a0;
            #pragma unroll
            for (int k = 0; k < C2; ++k) {
                float w = sdW2[o*C2 + k];
                a0 = fmaf(w, h0[k], a0);
                a1 = fmaf(w, h1[k], a1);
            }
            du[o] = fmaxf(a0, 0.f);
            dl[o] = fmaxf(a1, 0.f);
        }
    }

    // ---- composition upper: 4 blocks, xh0-half of conv1 shared ----
    float cu[HD];
    #pragma unroll
    for (int o = 0; o < HD; ++o) cu[o] = 0.f;
    {
        float pre[C2];
        #pragma unroll
        for (int o = 0; o < C2; ++o) {
            float a = suB1[o];
            #pragma unroll
            for (int k = 0; k < HD; ++k) a = fmaf(suW1[o*C2 + k], vxh0[k], a);
            pre[o] = a;
        }
        for (int i = 0; i < 4; ++i) {
            float xpi[HD];
            #pragma unroll
            for (int c = 0; c < HD; ++c)
                xpi[c] = xp[i*CHW + base + c*PIX] * cau;
            float h[C2];
            #pragma unroll
            for (int o = 0; o < C2; ++o) {
                float a = pre[o];
                #pragma unroll
                for (int k = 0; k < HD; ++k) a = fmaf(suW1[o*C2 + HD + k], xpi[k], a);
                h[o] = fmaxf(a, 0.f);
            }
            #pragma unroll
            for (int o = 0; o < HD; ++o) {
                float a = suB2[o];
                #pragma unroll
                for (int k = 0; k < C2; ++k) a = fmaf(suW2[o*C2 + k], h[k], a);
                cu[o] += fmaxf(a, 0.f);
            }
        }
    }

    // ---- composition lower: 2 blocks ----
    float cl[HD];
    #pragma unroll
    for (int o = 0; o < HD; ++o) cl[o] = 0.f;
    {
        float pre[C2];
        #pragma unroll
        for (int o = 0; o < C2; ++o) {
            float a = slB1[o];
            #pragma unroll
            for (int k = 0; k < HD; ++k) a = fmaf(slW1[o*C2 + k], vxh1[k], a);
            pre[o] = a;
        }
        for (int i = 4; i < 6; ++i) {
            float xpi[HD];
            #pragma unroll
            for (int c = 0; c < HD; ++c)
                xpi[c] = xp[i*CHW + base + c*PIX] * cal;
            float h[C2];
            #pragma unroll
            for (int o = 0; o < C2; ++o) {
                float a = pre[o];
                #pragma unroll
                for (int k = 0; k < HD; ++k) a = fmaf(slW1[o*C2 + HD + k], xpi[k], a);
                h[o] = fmaxf(a, 0.f);
            }
            #pragma unroll
            for (int o = 0; o < HD; ++o) {
                float a = slB2[o];
                #pragma unroll
                for (int k = 0; k < C2; ++k) a = fmaf(slW2[o*C2 + k], h[k], a);
                cl[o] += fmaxf(a, 0.f);
            }
        }
    }

    // ---- GRUs ----
    float mu[HD], ml[HD], xhu[HD], xhl[HD];
    #pragma unroll
    for (int c = 0; c < HD; ++c) { mu[c] = du[c] + cu[c]; ml[c] = dl[c] + cl[c]; }
    gru10(vxh0, mu, sgWg[0], sgBg[0], sgWc[0], sgBc[0], xhu);
    gru10(vxh1, ml, sgWg[1], sgBg[1], sgWc[1], sgBc[1], xhl);

    #pragma unroll
    for (int c = 0; c < HD; ++c) {
        out[base + c*PIX]       = xhu[c];
        out[CHW + base + c*PIX] = xhl[c];
    }
}

extern "C" void kernel_launch(void* const* d_in, const int* in_sizes, int n_in,
                              void* d_out, int out_size, void* d_ws, size_t ws_size,
                              hipStream_t stream) {
    const float* xf    = (const float*)d_in[0];
    const float* xh    = (const float*)d_in[1];
    const float* xp    = (const float*)d_in[2];
    const float* h_att = (const float*)d_in[3];
    const float* p_att = (const float*)d_in[4];
    const float* dW1   = (const float*)d_in[5];
    const float* dbn1  = (const float*)d_in[6];
    const float* dW2   = (const float*)d_in[7];
    const float* dbn2  = (const float*)d_in[8];
    const float* uW1   = (const float*)d_in[9];
    const float* ubn1  = (const float*)d_in[10];
    const float* uW2   = (const float*)d_in[11];
    const float* ubn2  = (const float*)d_in[12];
    const float* lW1   = (const float*)d_in[13];
    const float* lbn1  = (const float*)d_in[14];
    const float* lW2   = (const float*)d_in[15];
    const float* lbn2  = (const float*)d_in[16];
    const float* guWg  = (const float*)d_in[17];
    const float* gubg  = (const float*)d_in[18];
    const float* guWc  = (const float*)d_in[19];
    const float* gubc  = (const float*)d_in[20];
    const float* glWg  = (const float*)d_in[21];
    const float* glbg  = (const float*)d_in[22];
    const float* glWc  = (const float*)d_in[23];
    const float* glbc  = (const float*)d_in[24];

    dim3 grid(NPIX / 256), block(256);
    half_graph_fused<<<grid, block, 0, stream>>>(
        xf, xh, xp, h_att, p_att,
        dW1, dbn1, dW2, dbn2,
        uW1, ubn1, uW2, ubn2,
        lW1, lbn1, lW2, lbn2,
        guWg, gubg, guWc, gubc,
        glWg, glbg, glWc, glbc,
        (float*)d_out);
}

// Round 3
// 117.804 us; speedup vs baseline: 4.5792x; 4.5792x over previous
//
#include <hip/hip_runtime.h>

#define HD 10
#define C2 20
#define PIX (192*192)
#define NB 8
#define NPIX (NB*PIX)
#define CHW (NB*HD*PIX)
#define EPSB 1e-5f

__device__ __forceinline__ float sigm(float x) {
    return __builtin_amdgcn_rcpf(1.0f + __expf(-x));
}
__device__ __forceinline__ float tanh_fast(float x) {
    return 1.0f - 2.0f * __builtin_amdgcn_rcpf(1.0f + __expf(2.0f * x));
}

// Single fused kernel: no workspace, no cross-kernel dataflow (graph-replay safe).
// All weight/BN reads are wave-uniform with compile-time offsets -> scalar loads.
__global__ __launch_bounds__(256) void half_kernel(
    const float* __restrict__ xf, const float* __restrict__ xh, const float* __restrict__ xp,
    const float* __restrict__ h_att, const float* __restrict__ p_att,
    const float* __restrict__ dW1, const float* __restrict__ dbn1,
    const float* __restrict__ dW2, const float* __restrict__ dbn2,
    const float* __restrict__ uW1, const float* __restrict__ ubn1,
    const float* __restrict__ uW2, const float* __restrict__ ubn2,
    const float* __restrict__ lW1, const float* __restrict__ lbn1,
    const float* __restrict__ lW2, const float* __restrict__ lbn2,
    const float* __restrict__ guWg, const float* __restrict__ gubg,
    const float* __restrict__ guWc, const float* __restrict__ gubc,
    const float* __restrict__ glWg, const float* __restrict__ glbg,
    const float* __restrict__ glWc, const float* __restrict__ glbc,
    float* __restrict__ out)
{
    const int half = blockIdx.y;                 // 0 = upper, 1 = lower (uniform)
    const int t = blockIdx.x * 256 + threadIdx.x;
    const int b = t / PIX;                        // uniform per block (PIX % 256 == 0)
    const int s = t - b * PIX;
    const int base  = b * (HD*PIX) + s;           // [B,HD,P] tensors: + c*PIX
    const int abase = b * PIX + s;                // [*,B,1,P] attention maps

    // wave-uniform weight/BN pointers (selected by uniform `half`)
    const float* Wc1  = half ? lW1  : uW1;
    const float* cbn1 = half ? lbn1 : ubn1;
    const float* Wc2  = half ? lW2  : uW2;
    const float* cbn2 = half ? lbn2 : ubn2;
    const float* Wg = half ? glWg : guWg;
    const float* bg = half ? glbg : gubg;
    const float* Wc = half ? glWc : guWc;
    const float* bc = half ? glbc : gubc;

    const float* xhh = xh + half * CHW;
    float* outh = out + half * CHW;

    float vxh[HD];
    #pragma unroll
    for (int c = 0; c < HD; ++c) vxh[c] = xhh[base + c*PIX];

    const float ha = h_att[(1 + half) * NPIX + abase];
    float catt = 0.f;
    {
        const int mstart = half ? 5 : 1;
        const int natt   = half ? 2 : 4;
        for (int j = 0; j < natt; ++j) catt += p_att[(mstart + j) * NPIX + abase];
    }

    // ---- decomposition block -> message accumulator m (BN applied inline, transient s/t) ----
    float m[HD];
    {
        float in[C2];
        #pragma unroll
        for (int c = 0; c < HD; ++c) { in[c] = xf[base + c*PIX] * ha; in[HD + c] = vxh[c]; }
        float h[C2];
        #pragma unroll
        for (int o = 0; o < C2; ++o) {
            float a = 0.f;
            #pragma unroll
            for (int k = 0; k < C2; ++k) a = fmaf(dW1[o*C2 + k], in[k], a);
            float sc = dbn1[o] * rsqrtf(dbn1[3*C2 + o] + EPSB);
            float tr = dbn1[C2 + o] - sc * dbn1[2*C2 + o];
            h[o] = fmaxf(fmaf(a, sc, tr), 0.f);
        }
        #pragma unroll
        for (int o = 0; o < HD; ++o) {
            float a = 0.f;
            #pragma unroll
            for (int k = 0; k < C2; ++k) a = fmaf(dW2[o*C2 + k], h[k], a);
            float sc = dbn2[o] * rsqrtf(dbn2[3*HD + o] + EPSB);
            float tr = dbn2[HD + o] - sc * dbn2[2*HD + o];
            m[o] = fmaxf(fmaf(a, sc, tr), 0.f);
        }
    }

    // ---- composition blocks ----
    {
        // cached per-path BN constants (uniform registers, reused across parts)
        float s1[C2], s2[HD], t2[HD];
        #pragma unroll
        for (int o = 0; o < C2; ++o)
            s1[o] = cbn1[o] * rsqrtf(cbn1[3*C2 + o] + EPSB);
        #pragma unroll
        for (int o = 0; o < HD; ++o) {
            s2[o] = cbn2[o] * rsqrtf(cbn2[3*HD + o] + EPSB);
            t2[o] = cbn2[HD + o] - s2[o] * cbn2[2*HD + o];
        }
        // pre[] = BN-affine of the shared xh-half of conv1 (t1 folded in, transient)
        float pre[C2];
        #pragma unroll
        for (int o = 0; o < C2; ++o) {
            float a = 0.f;
            #pragma unroll
            for (int k = 0; k < HD; ++k) a = fmaf(Wc1[o*C2 + k], vxh[k], a);
            float t1 = cbn1[C2 + o] - s1[o] * cbn1[2*C2 + o];
            pre[o] = fmaf(a, s1[o], t1);
        }
        const int pstart = half ? 4 : 0;
        const int nparts = half ? 2 : 4;
        for (int i = 0; i < nparts; ++i) {        // runtime loop: bounds live range
            float xpi[HD];
            #pragma unroll
            for (int c = 0; c < HD; ++c)
                xpi[c] = xp[(pstart + i) * CHW + base + c*PIX] * catt;
            float h[C2];
            #pragma unroll
            for (int o = 0; o < C2; ++o) {
                float a = 0.f;
                #pragma unroll
                for (int k = 0; k < HD; ++k) a = fmaf(Wc1[o*C2 + HD + k], xpi[k], a);
                h[o] = fmaxf(fmaf(a, s1[o], pre[o]), 0.f);
            }
            #pragma unroll
            for (int o = 0; o < HD; ++o) {
                float a = 0.f;
                #pragma unroll
                for (int k = 0; k < C2; ++k) a = fmaf(Wc2[o*C2 + k], h[k], a);
                m[o] += fmaxf(fmaf(a, s2[o], t2[o]), 0.f);
            }
        }
    }

    // ---- GRU ----
    float g[C2];
    #pragma unroll
    for (int o = 0; o < C2; ++o) {
        float a = bg[o];
        #pragma unroll
        for (int k = 0; k < HD; ++k) a = fmaf(Wg[o*C2 + k], m[k], a);
        #pragma unroll
        for (int k = 0; k < HD; ++k) a = fmaf(Wg[o*C2 + HD + k], vxh[k], a);
        g[o] = sigm(a);
    }
    float rh[HD];
    #pragma unroll
    for (int k = 0; k < HD; ++k) rh[k] = g[k] * vxh[k];
    #pragma unroll
    for (int o = 0; o < HD; ++o) {
        float a = bc[o];
        #pragma unroll
        for (int k = 0; k < HD; ++k) a = fmaf(Wc[o*C2 + k], m[k], a);
        #pragma unroll
        for (int k = 0; k < HD; ++k) a = fmaf(Wc[o*C2 + HD + k], rh[k], a);
        float c = tanh_fast(a);
        float u = g[HD + o];
        outh[base + o*PIX] = fmaf(u, c - vxh[o], vxh[o]);   // (1-u)*h + u*c
    }
}

extern "C" void kernel_launch(void* const* d_in, const int* in_sizes, int n_in,
                              void* d_out, int out_size, void* d_ws, size_t ws_size,
                              hipStream_t stream) {
    const float* xf    = (const float*)d_in[0];
    const float* xh    = (const float*)d_in[1];
    const float* xp    = (const float*)d_in[2];
    const float* h_att = (const float*)d_in[3];
    const float* p_att = (const float*)d_in[4];
    const float* dW1   = (const float*)d_in[5];
    const float* dbn1  = (const float*)d_in[6];
    const float* dW2   = (const float*)d_in[7];
    const float* dbn2  = (const float*)d_in[8];
    const float* uW1   = (const float*)d_in[9];
    const float* ubn1  = (const float*)d_in[10];
    const float* uW2   = (const float*)d_in[11];
    const float* ubn2  = (const float*)d_in[12];
    const float* lW1   = (const float*)d_in[13];
    const float* lbn1  = (const float*)d_in[14];
    const float* lW2   = (const float*)d_in[15];
    const float* lbn2  = (const float*)d_in[16];
    const float* guWg  = (const float*)d_in[17];
    const float* gubg  = (const float*)d_in[18];
    const float* guWc  = (const float*)d_in[19];
    const float* gubc  = (const float*)d_in[20];
    const float* glWg  = (const float*)d_in[21];
    const float* glbg  = (const float*)d_in[22];
    const float* glWc  = (const float*)d_in[23];
    const float* glbc  = (const float*)d_in[24];

    dim3 grid(NPIX / 256, 2), block(256);
    half_kernel<<<grid, block, 0, stream>>>(
        xf, xh, xp, h_att, p_att,
        dW1, dbn1, dW2, dbn2,
        uW1, ubn1, uW2, ubn2,
        lW1, lbn1, lW2, lbn2,
        guWg, gubg, guWc, gubc,
        glWg, glbg, glWc, glbc,
        (float*)d_out);
}